// Round 2
// baseline (73.680 us; speedup 1.0000x reference)
//
#include <hip/hip_runtime.h>
#include <math.h>

#define BB 8
#define SS 512
#define DD 256
#define PP (SS * (SS - 1) / 2)    // 130816 pairs per batch
#define TILES_PER_B (32 * 33 / 2) // 528 triangular 16x16 tiles per batch

typedef short bf16x8 __attribute__((ext_vector_type(8)));
typedef float f32x4 __attribute__((ext_vector_type(4)));

// fp32 -> bf16 round-to-nearest-even (finite inputs; no NaN path needed)
static __device__ inline unsigned short f2bf(float f) {
    unsigned int u = __float_as_uint(f);
    return (unsigned short)((u + 0x7fffu + ((u >> 16) & 1u)) >> 16);
}

// Fused: one wave per 16x16 lower-triangular tile pair.
// Loads fp32 rows straight from x (L2-resident), converts to bf16 inline,
// computes fp32 row norms inline (quad butterfly), Gram via MFMA,
// epilogue d = sqrt(max(ni+nj-2g, eps)).
__global__ __launch_bounds__(256) void dist_fused(const float* __restrict__ x,
                                                  float* __restrict__ out) {
    int w    = blockIdx.x * 4 + (threadIdx.x >> 6); // 0..4223
    int lane = threadIdx.x & 63;
    int b    = w / TILES_PER_B;
    int t    = w - b * TILES_PER_B;
    // largest ti with ti*(ti+1)/2 <= t (float guess + integer fixup)
    int ti = (int)((sqrtf(8.0f * (float)t + 1.0f) - 1.0f) * 0.5f);
    while ((ti + 1) * (ti + 2) / 2 <= t) ti++;
    while (ti * (ti + 1) / 2 > t) ti--;
    int tj = t - ti * (ti + 1) / 2;

    int il   = lane & 15; // row-in-tile for A (=> C row source) and B (=> C col)
    int quad = lane >> 4; // k-quad for operands; row-quad for C/D

    const float* arow = x + ((size_t)(b * SS + ti * 16 + il)) * DD + quad * 8;
    const float* brow = x + ((size_t)(b * SS + tj * 16 + il)) * DD + quad * 8;

    f32x4 acc = {0.f, 0.f, 0.f, 0.f};
    float na = 0.f, nb = 0.f;
    #pragma unroll
    for (int k = 0; k < DD; k += 32) {
        float4 a0 = *reinterpret_cast<const float4*>(arow + k);
        float4 a1 = *reinterpret_cast<const float4*>(arow + k + 4);
        float4 b0 = *reinterpret_cast<const float4*>(brow + k);
        float4 b1 = *reinterpret_cast<const float4*>(brow + k + 4);

        na += a0.x*a0.x + a0.y*a0.y + a0.z*a0.z + a0.w*a0.w
            + a1.x*a1.x + a1.y*a1.y + a1.z*a1.z + a1.w*a1.w;
        nb += b0.x*b0.x + b0.y*b0.y + b0.z*b0.z + b0.w*b0.w
            + b1.x*b1.x + b1.y*b1.y + b1.z*b1.z + b1.w*b1.w;

        bf16x8 av, bv;
        av[0] = (short)f2bf(a0.x); av[1] = (short)f2bf(a0.y);
        av[2] = (short)f2bf(a0.z); av[3] = (short)f2bf(a0.w);
        av[4] = (short)f2bf(a1.x); av[5] = (short)f2bf(a1.y);
        av[6] = (short)f2bf(a1.z); av[7] = (short)f2bf(a1.w);
        bv[0] = (short)f2bf(b0.x); bv[1] = (short)f2bf(b0.y);
        bv[2] = (short)f2bf(b0.z); bv[3] = (short)f2bf(b0.w);
        bv[4] = (short)f2bf(b1.x); bv[5] = (short)f2bf(b1.y);
        bv[6] = (short)f2bf(b1.z); bv[7] = (short)f2bf(b1.w);

        acc = __builtin_amdgcn_mfma_f32_16x16x32_bf16(av, bv, acc, 0, 0, 0);
    }

    // lane (il,quad) holds partial ssq over k in {32*kk + quad*8 + j};
    // butterfly over the 4 quad-lanes of the same il -> full row norm on every lane
    na += __shfl_xor(na, 16); na += __shfl_xor(na, 32);
    nb += __shfl_xor(nb, 16); nb += __shfl_xor(nb, 32);

    // C/D layout (m89-verified): col = lane&15 -> j, row = quad*4+reg -> i
    int jg = tj * 16 + il;
    float* outb = out + (size_t)b * PP;
    #pragma unroll
    for (int r = 0; r < 4; r++) {
        int ig = ti * 16 + quad * 4 + r;
        float ni = __shfl(na, quad * 4 + r); // uniform call site, before divergence
        if (ig > jg) {
            float d2 = fmaxf(ni + nb - 2.0f * acc[r], 1e-7f);
            outb[(size_t)(ig * (ig - 1) / 2) + jg] = sqrtf(d2);
        }
    }
}

extern "C" void kernel_launch(void* const* d_in, const int* in_sizes, int n_in,
                              void* d_out, int out_size, void* d_ws, size_t ws_size,
                              hipStream_t stream) {
    const float* x = (const float*)d_in[0];
    float* out = (float*)d_out;
    // 4224 waves = 1056 blocks x 4 waves; single launch, no workspace use
    dist_fused<<<1056, 256, 0, stream>>>(x, out);
}

// Round 3
// 68.697 us; speedup vs baseline: 1.0725x; 1.0725x over previous
//
#include <hip/hip_runtime.h>
#include <math.h>

#define BB 8
#define SS 512
#define DD 256
#define PP (SS * (SS - 1) / 2)     // 130816 pairs per batch
#define TILES32 (16 * 17 / 2)      // 136 triangular 32x32 tiles per batch

typedef short bf16x8 __attribute__((ext_vector_type(8)));
typedef float f32x16 __attribute__((ext_vector_type(16)));

// fp32 -> bf16 round-to-nearest-even (finite inputs; no NaN path needed)
static __device__ inline unsigned short f2bf(float f) {
    unsigned int u = __float_as_uint(f);
    return (unsigned short)((u + 0x7fffu + ((u >> 16) & 1u)) >> 16);
}

// One wave per row: convert 256 fp32 -> bf16, compute fp32 sum of squares.
__global__ __launch_bounds__(256) void prep_kernel(const float* __restrict__ x,
                                                   unsigned short* __restrict__ xb,
                                                   float* __restrict__ norms) {
    int row  = blockIdx.x * 4 + (threadIdx.x >> 6); // 4096 rows total
    int lane = threadIdx.x & 63;
    const float4* src = reinterpret_cast<const float4*>(x + (size_t)row * DD) + lane;
    float4 v = *src;
    float ss = v.x * v.x + v.y * v.y + v.z * v.z + v.w * v.w;
    ushort4 pk;
    pk.x = f2bf(v.x); pk.y = f2bf(v.y); pk.z = f2bf(v.z); pk.w = f2bf(v.w);
    *reinterpret_cast<ushort4*>(xb + (size_t)row * DD + lane * 4) = pk;
    #pragma unroll
    for (int o = 32; o > 0; o >>= 1) ss += __shfl_down(ss, o);
    if (lane == 0) norms[row] = ss;
}

// One wave per 32x32 lower-triangular tile pair, mfma_f32_32x32x16_bf16.
// C/D layout (m74/m101-verified): col(n) = lane&31, row(m) = (reg&3)+8*(reg>>2)+4*(lane>>5).
__global__ __launch_bounds__(256) void dist32_kernel(const unsigned short* __restrict__ xb,
                                                     const float* __restrict__ norms,
                                                     float* __restrict__ out) {
    int w    = blockIdx.x * 4 + (threadIdx.x >> 6); // 0..1087
    int lane = threadIdx.x & 63;
    int b    = w / TILES32;
    int t    = w - b * TILES32;
    // largest ti with ti*(ti+1)/2 <= t
    int ti = (int)((sqrtf(8.0f * (float)t + 1.0f) - 1.0f) * 0.5f);
    while ((ti + 1) * (ti + 2) / 2 <= t) ti++;
    while (ti * (ti + 1) / 2 > t) ti--;
    int tj = t - ti * (ti + 1) / 2;

    int r32  = lane & 31; // m for A-source rows, n for B-source rows
    int half = lane >> 5; // k-half for operands; row-offset term for C/D

    const unsigned short* arow = xb + ((size_t)(b * SS + ti * 32 + r32)) * DD + half * 8;
    const unsigned short* brow = xb + ((size_t)(b * SS + tj * 32 + r32)) * DD + half * 8;

    f32x16 acc;
    #pragma unroll
    for (int i = 0; i < 16; i++) acc[i] = 0.0f;

    #pragma unroll
    for (int k = 0; k < DD; k += 16) {
        bf16x8 av = *reinterpret_cast<const bf16x8*>(arow + k);
        bf16x8 bv = *reinterpret_cast<const bf16x8*>(brow + k);
        acc = __builtin_amdgcn_mfma_f32_32x32x16_bf16(av, bv, acc, 0, 0, 0);
    }

    int jg = tj * 32 + r32;
    float nj = norms[b * SS + jg];
    float* outb = out + (size_t)b * PP;
    #pragma unroll
    for (int reg = 0; reg < 16; reg++) {
        int m  = (reg & 3) + 8 * (reg >> 2) + 4 * half;
        int ig = ti * 32 + m;
        if (ig > jg) {
            float ni = norms[b * SS + ig];
            float d2 = fmaxf(ni + nj - 2.0f * acc[reg], 1e-7f);
            outb[(size_t)(ig * (ig - 1) / 2) + jg] = sqrtf(d2);
        }
    }
}

extern "C" void kernel_launch(void* const* d_in, const int* in_sizes, int n_in,
                              void* d_out, int out_size, void* d_ws, size_t ws_size,
                              hipStream_t stream) {
    const float* x = (const float*)d_in[0];
    float* out = (float*)d_out;
    unsigned short* xb = (unsigned short*)d_ws;                      // 2 MB bf16 copy
    float* norms = (float*)((char*)d_ws + (size_t)BB * SS * DD * 2); // 16 KB norms

    prep_kernel<<<1024, 256, 0, stream>>>(x, xb, norms);
    dist32_kernel<<<272, 256, 0, stream>>>(xb, norms, out); // 1088 waves
}